// Round 2
// baseline (607.075 us; speedup 1.0000x reference)
//
#include <hip/hip_runtime.h>
#include <hip/hip_bf16.h>

// Pipeline (restructured: GEMM-before-aggregate, since mean_agg is linear):
//   xl = x @ W1l                    (GEMM 128->128)
//   t  = mean_agg(xl)               (CSR gather, 128-wide)
//   h  = relu(x @ W1r + t + b1)     (GEMM 128->128, fused addend+bias+relu)
//   hl = h @ W2l                    (GEMM 128->64)
//   t2 = mean_agg(hl)               (CSR gather, 64-wide)
//   out= h @ W2r + t2 + b2          (GEMM 128->64, fused addend+bias)

__global__ void count_deg_k(const int* __restrict__ dstv, int* __restrict__ cnt, int E) {
    int e = blockIdx.x * blockDim.x + threadIdx.x;
    if (e < E) atomicAdd(&cnt[dstv[e]], 1);
}

// Single-block exclusive scan over cnt[0..n) -> rowptr/pos, plus inv_deg.
__global__ void scan_k(const int* __restrict__ cnt, int* __restrict__ rowptr,
                       int* __restrict__ pos, float* __restrict__ inv_deg, int n) {
    __shared__ int sdata[256];
    int t = threadIdx.x;
    int chunk = (n + 255) / 256;
    int lo = t * chunk;
    int hi = min(n, lo + chunk);
    int s = 0;
    for (int i = lo; i < hi; ++i) s += cnt[i];
    sdata[t] = s;
    __syncthreads();
    // Hillis-Steele inclusive scan of 256 partial sums
    for (int off = 1; off < 256; off <<= 1) {
        int v = (t >= off) ? sdata[t - off] : 0;
        __syncthreads();
        sdata[t] += v;
        __syncthreads();
    }
    int base = sdata[t] - s;  // exclusive prefix
    for (int i = lo; i < hi; ++i) {
        int c = cnt[i];
        rowptr[i] = base;
        pos[i] = base;
        inv_deg[i] = 1.0f / (float)max(c, 1);
        base += c;
    }
    if (t == 255) rowptr[n] = base;  // == E
}

__global__ void fill_k(const int* __restrict__ srcv, const int* __restrict__ dstv,
                       int* __restrict__ pos, int* __restrict__ csr, int E) {
    int e = blockIdx.x * blockDim.x + threadIdx.x;
    if (e < E) {
        int p = atomicAdd(&pos[dstv[e]], 1);
        csr[p] = srcv[e];
    }
}

// One wave per destination node; lane-parallel over features.
template<int F>
__global__ __launch_bounds__(256) void agg_k(const float* __restrict__ feat,
                                             const int* __restrict__ rowptr,
                                             const int* __restrict__ csr,
                                             const float* __restrict__ inv_deg,
                                             float* __restrict__ out, int n) {
    int wid = (blockIdx.x * 256 + threadIdx.x) >> 6;
    int lane = threadIdx.x & 63;
    if (wid >= n) return;
    int s = rowptr[wid], e = rowptr[wid + 1];
    float sc = inv_deg[wid];
    if (F == 128) {
        float ax = 0.f, ay = 0.f;
        for (int p = s; p < e; ++p) {
            int u = csr[p];
            float2 v = *reinterpret_cast<const float2*>(&feat[(size_t)u * 128 + lane * 2]);
            ax += v.x; ay += v.y;
        }
        float2 r; r.x = ax * sc; r.y = ay * sc;
        *reinterpret_cast<float2*>(&out[(size_t)wid * 128 + lane * 2]) = r;
    } else {
        float acc = 0.f;
        for (int p = s; p < e; ++p) acc += feat[(size_t)csr[p] * F + lane];
        out[(size_t)wid * F + lane] = acc * sc;
    }
}

// C[n,NC] = A[n,128] @ W[128,NC] (+D)(+bias)(relu). 64-row tiles, 256 threads.
template<int NC, bool HAS_D, bool HAS_BIAS, bool RELU>
__global__ __launch_bounds__(256) void gemm_k(const float* __restrict__ A,
                                              const float* __restrict__ W,
                                              const float* __restrict__ D,
                                              const float* __restrict__ bias,
                                              float* __restrict__ C, int n) {
    constexpr int ASTR = 132;           // pad: f4-aligned (132*4B%16==0), conflict-free reads
    constexpr int NG = NC / 64;         // column groups of 64
    __shared__ float At[64 * ASTR];
    __shared__ float Wt[32 * NC];
    int t = threadIdx.x;
    int brow = blockIdx.x * 64;

    // Stage full A tile: 64 rows x 128 cols
    #pragma unroll
    for (int i = 0; i < 8; ++i) {
        int idx = t + 256 * i;
        int r = idx >> 5, f4 = idx & 31;
        int grow = brow + r;
        float4 v = make_float4(0.f, 0.f, 0.f, 0.f);
        if (grow < n) v = *reinterpret_cast<const float4*>(&A[(size_t)grow * 128 + f4 * 4]);
        *reinterpret_cast<float4*>(&At[r * ASTR + f4 * 4]) = v;
    }

    int tx = t & 15, ty = t >> 4;
    float4 acc[4][NG];
    #pragma unroll
    for (int r = 0; r < 4; ++r)
        #pragma unroll
        for (int g = 0; g < NG; ++g) acc[r][g] = make_float4(0.f, 0.f, 0.f, 0.f);

    for (int kc = 0; kc < 4; ++kc) {
        __syncthreads();
        // Stage W rows [kc*32, kc*32+32)
        constexpr int NW = (32 * NC) / 4 / 256;
        #pragma unroll
        for (int i = 0; i < NW; ++i) {
            int idx = (t + 256 * i) * 4;
            int wr = idx / NC, wc = idx % NC;
            *reinterpret_cast<float4*>(&Wt[wr * NC + wc]) =
                *reinterpret_cast<const float4*>(&W[(size_t)(kc * 32 + wr) * NC + wc]);
        }
        __syncthreads();
        #pragma unroll
        for (int k = 0; k < 32; ++k) {
            int kk = kc * 32 + k;
            float a0 = At[(ty * 4 + 0) * ASTR + kk];
            float a1 = At[(ty * 4 + 1) * ASTR + kk];
            float a2 = At[(ty * 4 + 2) * ASTR + kk];
            float a3 = At[(ty * 4 + 3) * ASTR + kk];
            #pragma unroll
            for (int g = 0; g < NG; ++g) {
                float4 b = *reinterpret_cast<const float4*>(&Wt[k * NC + g * 64 + tx * 4]);
                acc[0][g].x += a0 * b.x; acc[0][g].y += a0 * b.y; acc[0][g].z += a0 * b.z; acc[0][g].w += a0 * b.w;
                acc[1][g].x += a1 * b.x; acc[1][g].y += a1 * b.y; acc[1][g].z += a1 * b.z; acc[1][g].w += a1 * b.w;
                acc[2][g].x += a2 * b.x; acc[2][g].y += a2 * b.y; acc[2][g].z += a2 * b.z; acc[2][g].w += a2 * b.w;
                acc[3][g].x += a3 * b.x; acc[3][g].y += a3 * b.y; acc[3][g].z += a3 * b.z; acc[3][g].w += a3 * b.w;
            }
        }
    }

    #pragma unroll
    for (int r = 0; r < 4; ++r) {
        int grow = brow + ty * 4 + r;
        if (grow >= n) continue;
        #pragma unroll
        for (int g = 0; g < NG; ++g) {
            int col = g * 64 + tx * 4;
            float4 v = acc[r][g];
            if (HAS_D) {
                float4 d = *reinterpret_cast<const float4*>(&D[(size_t)grow * NC + col]);
                v.x += d.x; v.y += d.y; v.z += d.z; v.w += d.w;
            }
            if (HAS_BIAS) {
                float4 bb = *reinterpret_cast<const float4*>(&bias[col]);
                v.x += bb.x; v.y += bb.y; v.z += bb.z; v.w += bb.w;
            }
            if (RELU) {
                v.x = fmaxf(v.x, 0.f); v.y = fmaxf(v.y, 0.f);
                v.z = fmaxf(v.z, 0.f); v.w = fmaxf(v.w, 0.f);
            }
            *reinterpret_cast<float4*>(&C[(size_t)grow * NC + col]) = v;
        }
    }
}

extern "C" void kernel_launch(void* const* d_in, const int* in_sizes, int n_in,
                              void* d_out, int out_size, void* d_ws, size_t ws_size,
                              hipStream_t stream) {
    const float* x   = (const float*)d_in[0];
    const int*   edge= (const int*)d_in[1];
    const float* W1l = (const float*)d_in[2];
    const float* W1r = (const float*)d_in[3];
    const float* b1  = (const float*)d_in[4];
    const float* W2l = (const float*)d_in[5];
    const float* W2r = (const float*)d_in[6];
    const float* b2  = (const float*)d_in[7];
    float* out = (float*)d_out;

    const int N = in_sizes[0] / 128;
    const int E = in_sizes[1] / 2;
    const int* srcv = edge;        // edge_index row 0
    const int* dstv = edge + E;    // edge_index row 1

    char* p = (char*)d_ws;
    auto alloc = [&](size_t bytes) {
        char* q = p;
        p += ((bytes + 255) & ~(size_t)255);
        return q;
    };
    int*   cnt    = (int*)alloc((size_t)N * 4);
    int*   rowptr = (int*)alloc((size_t)(N + 1) * 4);
    int*   pos    = (int*)alloc((size_t)N * 4);
    int*   csr    = (int*)alloc((size_t)E * 4);
    float* invd   = (float*)alloc((size_t)N * 4);
    float* B0     = (float*)alloc((size_t)N * 128 * 4);  // xl, then h
    float* B1     = (float*)alloc((size_t)N * 128 * 4);  // t; later hl (first N*64) + t2 (second N*64)
    float* hl     = B1;
    float* t2     = B1 + (size_t)N * 64;

    hipMemsetAsync(cnt, 0, (size_t)N * 4, stream);
    count_deg_k<<<(E + 255) / 256, 256, 0, stream>>>(dstv, cnt, E);
    scan_k<<<1, 256, 0, stream>>>(cnt, rowptr, pos, invd, N);
    fill_k<<<(E + 255) / 256, 256, 0, stream>>>(srcv, dstv, pos, csr, E);

    int gb = (N + 63) / 64;
    int ab = (N + 3) / 4;
    // xl = x @ W1l
    gemm_k<128, false, false, false><<<gb, 256, 0, stream>>>(x, W1l, nullptr, nullptr, B0, N);
    // t = mean_agg(xl)
    agg_k<128><<<ab, 256, 0, stream>>>(B0, rowptr, csr, invd, B1, N);
    // h = relu(x @ W1r + t + b1)   (overwrites B0)
    gemm_k<128, true, true, true><<<gb, 256, 0, stream>>>(x, W1r, B1, b1, B0, N);
    // hl = h @ W2l
    gemm_k<64, false, false, false><<<gb, 256, 0, stream>>>(B0, W2l, nullptr, nullptr, hl, N);
    // t2 = mean_agg(hl)
    agg_k<64><<<ab, 256, 0, stream>>>(hl, rowptr, csr, invd, t2, N);
    // out = h @ W2r + t2 + b2
    gemm_k<64, true, true, false><<<gb, 256, 0, stream>>>(B0, W2r, t2, b2, out, N);
}

// Round 5
// 467.607 us; speedup vs baseline: 1.2983x; 1.2983x over previous
//
#include <hip/hip_runtime.h>
#include <hip/hip_bf16.h>

// Pipeline (restructured: GEMM-before-aggregate, since mean_agg is linear):
//   xl = x @ W1l                    (GEMM 128->128)
//   t  = mean_agg(xl)               (CSR gather, 128-wide)
//   h  = relu(x @ W1r + t + b1)     (GEMM 128->128, fused addend+bias+relu)
//   hl = h @ W2l                    (GEMM 128->64)
//   t2 = mean_agg(hl)               (CSR gather, 64-wide)
//   out= h @ W2r + t2 + b2          (GEMM 128->64, fused addend+bias)
// CSR build: histogram -> 3-kernel device-wide scan -> counting-sort fill.
// (R2 profile: single-block scan was 149us/607us; parallelized here.)

__global__ void count_deg_k(const int* __restrict__ dstv, int* __restrict__ cnt, int E) {
    int e = blockIdx.x * blockDim.x + threadIdx.x;
    if (e < E) atomicAdd(&cnt[dstv[e]], 1);
}

// ---- device-wide exclusive scan over cnt[0..n), 1024 elems per block ----
__global__ __launch_bounds__(256) void blocksum_k(const int* __restrict__ cnt,
                                                  int* __restrict__ bsum, int n) {
    __shared__ int red[4];
    int b = blockIdx.x, t = threadIdx.x;
    int base = b * 1024 + t * 4;
    int s = 0;
    #pragma unroll
    for (int i = 0; i < 4; ++i) { int idx = base + i; if (idx < n) s += cnt[idx]; }
    #pragma unroll
    for (int off = 32; off > 0; off >>= 1) s += __shfl_down(s, off);
    if ((t & 63) == 0) red[t >> 6] = s;
    __syncthreads();
    if (t == 0) bsum[b] = red[0] + red[1] + red[2] + red[3];
}

__global__ __launch_bounds__(256) void bscan_k(int* __restrict__ bsum, int nb) {
    __shared__ int sd[256];
    int t = threadIdx.x;
    int v = (t < nb) ? bsum[t] : 0;
    sd[t] = v;
    __syncthreads();
    for (int off = 1; off < 256; off <<= 1) {
        int u = (t >= off) ? sd[t - off] : 0;
        __syncthreads();
        sd[t] += u;
        __syncthreads();
    }
    if (t < nb) bsum[t] = sd[t] - v;  // exclusive
}

__global__ __launch_bounds__(256) void scanout_k(const int* __restrict__ cnt,
                                                 const int* __restrict__ bbase,
                                                 int* __restrict__ rowptr,
                                                 int* __restrict__ pos,
                                                 float* __restrict__ inv_deg,
                                                 int n, int E) {
    __shared__ int sums[256];
    int b = blockIdx.x, t = threadIdx.x;
    int base = b * 1024 + t * 4;
    int v[4];
    int s = 0;
    #pragma unroll
    for (int i = 0; i < 4; ++i) {
        int idx = base + i;
        v[i] = (idx < n) ? cnt[idx] : 0;
        s += v[i];
    }
    sums[t] = s;
    __syncthreads();
    for (int off = 1; off < 256; off <<= 1) {
        int u = (t >= off) ? sums[t - off] : 0;
        __syncthreads();
        sums[t] += u;
        __syncthreads();
    }
    int pre = sums[t] - s + bbase[b];  // exclusive prefix for this thread's run
    #pragma unroll
    for (int i = 0; i < 4; ++i) {
        int idx = base + i;
        if (idx < n) {
            rowptr[idx] = pre;
            pos[idx] = pre;
            inv_deg[idx] = 1.0f / (float)max(v[i], 1);
            pre += v[i];
        }
    }
    if (b == 0 && t == 0) rowptr[n] = E;
}

__global__ void fill_k(const int* __restrict__ srcv, const int* __restrict__ dstv,
                       int* __restrict__ pos, int* __restrict__ csr, int E) {
    int e = blockIdx.x * blockDim.x + threadIdx.x;
    if (e < E) {
        int p = atomicAdd(&pos[dstv[e]], 1);
        csr[p] = srcv[e];
    }
}

// One wave per destination node; lane-parallel over features.
template<int F>
__global__ __launch_bounds__(256) void agg_k(const float* __restrict__ feat,
                                             const int* __restrict__ rowptr,
                                             const int* __restrict__ csr,
                                             const float* __restrict__ inv_deg,
                                             float* __restrict__ out, int n) {
    int wid = (blockIdx.x * 256 + threadIdx.x) >> 6;
    int lane = threadIdx.x & 63;
    if (wid >= n) return;
    int s = rowptr[wid], e = rowptr[wid + 1];
    float sc = inv_deg[wid];
    if (F == 128) {
        float ax = 0.f, ay = 0.f;
        for (int p = s; p < e; ++p) {
            int u = csr[p];
            float2 v = *reinterpret_cast<const float2*>(&feat[(size_t)u * 128 + lane * 2]);
            ax += v.x; ay += v.y;
        }
        float2 r; r.x = ax * sc; r.y = ay * sc;
        *reinterpret_cast<float2*>(&out[(size_t)wid * 128 + lane * 2]) = r;
    } else {
        float acc = 0.f;
        for (int p = s; p < e; ++p) acc += feat[(size_t)csr[p] * F + lane];
        out[(size_t)wid * F + lane] = acc * sc;
    }
}

// C[n,NC] = A[n,128] @ W[128,NC] (+D)(+bias)(relu). 64-row tiles, 256 threads.
template<int NC, bool HAS_D, bool HAS_BIAS, bool RELU>
__global__ __launch_bounds__(256) void gemm_k(const float* __restrict__ A,
                                              const float* __restrict__ W,
                                              const float* __restrict__ D,
                                              const float* __restrict__ bias,
                                              float* __restrict__ C, int n) {
    constexpr int ASTR = 132;           // pad: f4-aligned (132*4B%16==0), conflict-free reads
    constexpr int NG = NC / 64;         // column groups of 64
    __shared__ float At[64 * ASTR];
    __shared__ float Wt[32 * NC];
    int t = threadIdx.x;
    int brow = blockIdx.x * 64;

    // Stage full A tile: 64 rows x 128 cols
    #pragma unroll
    for (int i = 0; i < 8; ++i) {
        int idx = t + 256 * i;
        int r = idx >> 5, f4 = idx & 31;
        int grow = brow + r;
        float4 v = make_float4(0.f, 0.f, 0.f, 0.f);
        if (grow < n) v = *reinterpret_cast<const float4*>(&A[(size_t)grow * 128 + f4 * 4]);
        *reinterpret_cast<float4*>(&At[r * ASTR + f4 * 4]) = v;
    }

    int tx = t & 15, ty = t >> 4;
    float4 acc[4][NG];
    #pragma unroll
    for (int r = 0; r < 4; ++r)
        #pragma unroll
        for (int g = 0; g < NG; ++g) acc[r][g] = make_float4(0.f, 0.f, 0.f, 0.f);

    for (int kc = 0; kc < 4; ++kc) {
        __syncthreads();
        // Stage W rows [kc*32, kc*32+32)
        constexpr int NW = (32 * NC) / 4 / 256;
        #pragma unroll
        for (int i = 0; i < NW; ++i) {
            int idx = (t + 256 * i) * 4;
            int wr = idx / NC, wc = idx % NC;
            *reinterpret_cast<float4*>(&Wt[wr * NC + wc]) =
                *reinterpret_cast<const float4*>(&W[(size_t)(kc * 32 + wr) * NC + wc]);
        }
        __syncthreads();
        #pragma unroll
        for (int k = 0; k < 32; ++k) {
            int kk = kc * 32 + k;
            float a0 = At[(ty * 4 + 0) * ASTR + kk];
            float a1 = At[(ty * 4 + 1) * ASTR + kk];
            float a2 = At[(ty * 4 + 2) * ASTR + kk];
            float a3 = At[(ty * 4 + 3) * ASTR + kk];
            #pragma unroll
            for (int g = 0; g < NG; ++g) {
                float4 b = *reinterpret_cast<const float4*>(&Wt[k * NC + g * 64 + tx * 4]);
                acc[0][g].x += a0 * b.x; acc[0][g].y += a0 * b.y; acc[0][g].z += a0 * b.z; acc[0][g].w += a0 * b.w;
                acc[1][g].x += a1 * b.x; acc[1][g].y += a1 * b.y; acc[1][g].z += a1 * b.z; acc[1][g].w += a1 * b.w;
                acc[2][g].x += a2 * b.x; acc[2][g].y += a2 * b.y; acc[2][g].z += a2 * b.z; acc[2][g].w += a2 * b.w;
                acc[3][g].x += a3 * b.x; acc[3][g].y += a3 * b.y; acc[3][g].z += a3 * b.z; acc[3][g].w += a3 * b.w;
            }
        }
    }

    #pragma unroll
    for (int r = 0; r < 4; ++r) {
        int grow = brow + ty * 4 + r;
        if (grow >= n) continue;
        #pragma unroll
        for (int g = 0; g < NG; ++g) {
            int col = g * 64 + tx * 4;
            float4 v = acc[r][g];
            if (HAS_D) {
                float4 d = *reinterpret_cast<const float4*>(&D[(size_t)grow * NC + col]);
                v.x += d.x; v.y += d.y; v.z += d.z; v.w += d.w;
            }
            if (HAS_BIAS) {
                float4 bb = *reinterpret_cast<const float4*>(&bias[col]);
                v.x += bb.x; v.y += bb.y; v.z += bb.z; v.w += bb.w;
            }
            if (RELU) {
                v.x = fmaxf(v.x, 0.f); v.y = fmaxf(v.y, 0.f);
                v.z = fmaxf(v.z, 0.f); v.w = fmaxf(v.w, 0.f);
            }
            *reinterpret_cast<float4*>(&C[(size_t)grow * NC + col]) = v;
        }
    }
}

extern "C" void kernel_launch(void* const* d_in, const int* in_sizes, int n_in,
                              void* d_out, int out_size, void* d_ws, size_t ws_size,
                              hipStream_t stream) {
    const float* x   = (const float*)d_in[0];
    const int*   edge= (const int*)d_in[1];
    const float* W1l = (const float*)d_in[2];
    const float* W1r = (const float*)d_in[3];
    const float* b1  = (const float*)d_in[4];
    const float* W2l = (const float*)d_in[5];
    const float* W2r = (const float*)d_in[6];
    const float* b2  = (const float*)d_in[7];
    float* out = (float*)d_out;

    const int N = in_sizes[0] / 128;
    const int E = in_sizes[1] / 2;
    const int* srcv = edge;        // edge_index row 0
    const int* dstv = edge + E;    // edge_index row 1

    char* p = (char*)d_ws;
    auto alloc = [&](size_t bytes) {
        char* q = p;
        p += ((bytes + 255) & ~(size_t)255);
        return q;
    };
    int*   cnt    = (int*)alloc((size_t)N * 4);
    int*   rowptr = (int*)alloc((size_t)(N + 1) * 4);
    int*   pos    = (int*)alloc((size_t)N * 4);
    int*   csr    = (int*)alloc((size_t)E * 4);
    float* invd   = (float*)alloc((size_t)N * 4);
    int*   bsum   = (int*)alloc((size_t)256 * 4);
    float* B0     = (float*)alloc((size_t)N * 128 * 4);  // xl, then h
    float* B1     = (float*)alloc((size_t)N * 128 * 4);  // t; later hl (first N*64) + t2 (second N*64)
    float* hl     = B1;
    float* t2     = B1 + (size_t)N * 64;

    int nb = (N + 1023) / 1024;   // scan blocks (<=256 supported; N<=262144)

    hipMemsetAsync(cnt, 0, (size_t)N * 4, stream);
    count_deg_k<<<(E + 255) / 256, 256, 0, stream>>>(dstv, cnt, E);
    blocksum_k<<<nb, 256, 0, stream>>>(cnt, bsum, N);
    bscan_k<<<1, 256, 0, stream>>>(bsum, nb);
    scanout_k<<<nb, 256, 0, stream>>>(cnt, bsum, rowptr, pos, invd, N, E);
    fill_k<<<(E + 255) / 256, 256, 0, stream>>>(srcv, dstv, pos, csr, E);

    int gb = (N + 63) / 64;
    int ab = (N + 3) / 4;
    // xl = x @ W1l
    gemm_k<128, false, false, false><<<gb, 256, 0, stream>>>(x, W1l, nullptr, nullptr, B0, N);
    // t = mean_agg(xl)
    agg_k<128><<<ab, 256, 0, stream>>>(B0, rowptr, csr, invd, B1, N);
    // h = relu(x @ W1r + t + b1)   (overwrites B0)
    gemm_k<128, true, true, true><<<gb, 256, 0, stream>>>(x, W1r, B1, b1, B0, N);
    // hl = h @ W2l
    gemm_k<64, false, false, false><<<gb, 256, 0, stream>>>(B0, W2l, nullptr, nullptr, hl, N);
    // t2 = mean_agg(hl)
    agg_k<64><<<ab, 256, 0, stream>>>(hl, rowptr, csr, invd, t2, N);
    // out = h @ W2r + t2 + b2
    gemm_k<64, true, true, false><<<gb, 256, 0, stream>>>(B0, W2r, t2, b2, out, N);
}

// Round 12
// 290.210 us; speedup vs baseline: 2.0918x; 1.6113x over previous
//
#include <hip/hip_runtime.h>
#include <hip/hip_bf16.h>

// bf16 pipeline (threshold 3.03e-2 = bf16 floor; fp32 accumulate everywhere):
//   xb  = bf16(x)
//   t   = mean_agg(xb)                       [128-wide bf16 gather]
//   h   = relu(xb@W1r + t@W1l + b1)          [fused 2-source MFMA GEMM -> bf16]
//   hl  = h@W2l                              [MFMA GEMM -> bf16]
//   t2  = mean_agg(hl)                       [64-wide bf16 gather]
//   out = h@W2r + t2 + b2                    [MFMA GEMM -> fp32]
// CSR build: histogram -> device-wide scan -> counting-sort fill (R3, verified).

typedef __attribute__((ext_vector_type(8))) short bf16x8;
typedef __attribute__((ext_vector_type(4))) float f32x4;

__device__ __forceinline__ ushort f2b(float f) {            // RNE fp32->bf16
    uint u = __float_as_uint(f);
    return (ushort)((u + 0x7fffu + ((u >> 16) & 1u)) >> 16);
}
__device__ __forceinline__ float b2f(ushort h) { return __uint_as_float(((uint)h) << 16); }
__device__ __forceinline__ float blo(uint u) { return __uint_as_float(u << 16); }
__device__ __forceinline__ float bhi(uint u) { return __uint_as_float(u & 0xffff0000u); }

// ---------------- CSR build ----------------
__global__ void count_deg_k(const int* __restrict__ dstv, int* __restrict__ cnt, int E) {
    int e = blockIdx.x * blockDim.x + threadIdx.x;
    if (e < E) atomicAdd(&cnt[dstv[e]], 1);
}

__global__ __launch_bounds__(256) void blocksum_k(const int* __restrict__ cnt,
                                                  int* __restrict__ bsum, int n) {
    __shared__ int red[4];
    int b = blockIdx.x, t = threadIdx.x;
    int base = b * 1024 + t * 4;
    int s = 0;
    #pragma unroll
    for (int i = 0; i < 4; ++i) { int idx = base + i; if (idx < n) s += cnt[idx]; }
    #pragma unroll
    for (int off = 32; off > 0; off >>= 1) s += __shfl_down(s, off);
    if ((t & 63) == 0) red[t >> 6] = s;
    __syncthreads();
    if (t == 0) bsum[b] = red[0] + red[1] + red[2] + red[3];
}

__global__ __launch_bounds__(256) void bscan_k(int* __restrict__ bsum, int nb) {
    __shared__ int sd[256];
    int t = threadIdx.x;
    int v = (t < nb) ? bsum[t] : 0;
    sd[t] = v;
    __syncthreads();
    for (int off = 1; off < 256; off <<= 1) {
        int u = (t >= off) ? sd[t - off] : 0;
        __syncthreads();
        sd[t] += u;
        __syncthreads();
    }
    if (t < nb) bsum[t] = sd[t] - v;
}

__global__ __launch_bounds__(256) void scanout_k(const int* __restrict__ cnt,
                                                 const int* __restrict__ bbase,
                                                 int* __restrict__ rowptr,
                                                 int* __restrict__ pos,
                                                 float* __restrict__ inv_deg,
                                                 int n, int E) {
    __shared__ int sums[256];
    int b = blockIdx.x, t = threadIdx.x;
    int base = b * 1024 + t * 4;
    int v[4];
    int s = 0;
    #pragma unroll
    for (int i = 0; i < 4; ++i) {
        int idx = base + i;
        v[i] = (idx < n) ? cnt[idx] : 0;
        s += v[i];
    }
    sums[t] = s;
    __syncthreads();
    for (int off = 1; off < 256; off <<= 1) {
        int u = (t >= off) ? sums[t - off] : 0;
        __syncthreads();
        sums[t] += u;
        __syncthreads();
    }
    int pre = sums[t] - s + bbase[b];
    #pragma unroll
    for (int i = 0; i < 4; ++i) {
        int idx = base + i;
        if (idx < n) {
            rowptr[idx] = pre;
            pos[idx] = pre;
            inv_deg[idx] = 1.0f / (float)max(v[i], 1);
            pre += v[i];
        }
    }
    if (b == 0 && t == 0) rowptr[n] = E;
}

__global__ void fill_k(const int* __restrict__ srcv, const int* __restrict__ dstv,
                       int* __restrict__ pos, int* __restrict__ csr, int E) {
    int e = blockIdx.x * blockDim.x + threadIdx.x;
    if (e < E) {
        int p = atomicAdd(&pos[dstv[e]], 1);
        csr[p] = srcv[e];
    }
}

// ---------------- dtype prep ----------------
__global__ void castx_k(const float* __restrict__ x, ushort* __restrict__ xb, int total4) {
    int i = blockIdx.x * blockDim.x + threadIdx.x;
    if (i < total4) {
        float4 v = reinterpret_cast<const float4*>(x)[i];
        ushort4 r;
        r.x = f2b(v.x); r.y = f2b(v.y); r.z = f2b(v.z); r.w = f2b(v.w);
        reinterpret_cast<ushort4*>(xb)[i] = r;
    }
}

// W^T (bf16, [n][k], k contiguous) for all four weights in one launch.
__global__ void prepw_k(const float* __restrict__ W1l, const float* __restrict__ W1r,
                        const float* __restrict__ W2l, const float* __restrict__ W2r,
                        ushort* __restrict__ w1lt, ushort* __restrict__ w1rt,
                        ushort* __restrict__ w2lt, ushort* __restrict__ w2rt) {
    int i = blockIdx.x * blockDim.x + threadIdx.x;   // 0..49151
    if (i < 16384) {
        int nn = i >> 7, k = i & 127;
        w1lt[i] = f2b(W1l[k * 128 + nn]);
    } else if (i < 32768) {
        int j = i - 16384, nn = j >> 7, k = j & 127;
        w1rt[j] = f2b(W1r[k * 128 + nn]);
    } else if (i < 40960) {
        int j = i - 32768, nn = j >> 7, k = j & 127;
        w2lt[j] = f2b(W2l[k * 64 + nn]);
    } else if (i < 49152) {
        int j = i - 40960, nn = j >> 7, k = j & 127;
        w2rt[j] = f2b(W2r[k * 64 + nn]);
    }
}

// ---------------- bf16 mean-aggregation: half-wave per node, 2-edge unroll ----------------
template<int F>
__global__ __launch_bounds__(256) void aggb_k(const ushort* __restrict__ feat,
                                              const int* __restrict__ rowptr,
                                              const int* __restrict__ csr,
                                              const float* __restrict__ invd,
                                              ushort* __restrict__ out, int n) {
    int tid = blockIdx.x * 256 + threadIdx.x;
    int node = tid >> 5;
    int sl = threadIdx.x & 31;
    if (node >= n) return;
    int s = rowptr[node], e = rowptr[node + 1];
    float sc = invd[node];
    if (F == 128) {           // lane owns 4 bf16 (8B); half-wave row = 256B
        float a0 = 0, a1 = 0, a2 = 0, a3 = 0;
        int p = s;
        for (; p + 2 <= e; p += 2) {
            int u0 = csr[p], u1 = csr[p + 1];
            uint2 v0 = *reinterpret_cast<const uint2*>(&feat[(size_t)u0 * 128 + sl * 4]);
            uint2 v1 = *reinterpret_cast<const uint2*>(&feat[(size_t)u1 * 128 + sl * 4]);
            a0 += blo(v0.x); a1 += bhi(v0.x); a2 += blo(v0.y); a3 += bhi(v0.y);
            a0 += blo(v1.x); a1 += bhi(v1.x); a2 += blo(v1.y); a3 += bhi(v1.y);
        }
        if (p < e) {
            uint2 v0 = *reinterpret_cast<const uint2*>(&feat[(size_t)csr[p] * 128 + sl * 4]);
            a0 += blo(v0.x); a1 += bhi(v0.x); a2 += blo(v0.y); a3 += bhi(v0.y);
        }
        ushort4 r;
        r.x = f2b(a0 * sc); r.y = f2b(a1 * sc); r.z = f2b(a2 * sc); r.w = f2b(a3 * sc);
        *reinterpret_cast<ushort4*>(&out[(size_t)node * 128 + sl * 4]) = r;
    } else {                  // F==64: lane owns 2 bf16 (4B); half-wave row = 128B
        float a0 = 0, a1 = 0;
        int p = s;
        for (; p + 2 <= e; p += 2) {
            int u0 = csr[p], u1 = csr[p + 1];
            uint v0 = *reinterpret_cast<const uint*>(&feat[(size_t)u0 * 64 + sl * 2]);
            uint v1 = *reinterpret_cast<const uint*>(&feat[(size_t)u1 * 64 + sl * 2]);
            a0 += blo(v0) + blo(v1); a1 += bhi(v0) + bhi(v1);
        }
        if (p < e) {
            uint v0 = *reinterpret_cast<const uint*>(&feat[(size_t)csr[p] * 64 + sl * 2]);
            a0 += blo(v0); a1 += bhi(v0);
        }
        ushort2 r;
        r.x = f2b(a0 * sc); r.y = f2b(a1 * sc);
        *reinterpret_cast<ushort2*>(&out[(size_t)node * 64 + sl * 2]) = r;
    }
}

// ---------------- MFMA GEMM: C[n,NC] = sum_src A_s[n,128] @ B_s[128,NC] (+add)(+bias)(relu)
// B passed pre-transposed bf16 [NC][128] (k contiguous). 64 rows/block, 4 waves,
// wave covers 16 rows x NC cols. 16x16x32 bf16 MFMA; C/D: col=lane&15, row=(lane>>4)*4+r.
template<int NC, int NSRC, bool RELU, bool OUT_BF16, bool HAS_BIAS, bool HAS_ADD>
__global__ __launch_bounds__(256) void mgemm_k(const ushort* __restrict__ A0,
                                               const ushort* __restrict__ B0,
                                               const ushort* __restrict__ A1,
                                               const ushort* __restrict__ B1,
                                               const ushort* __restrict__ addm,
                                               const float* __restrict__ bias,
                                               void* __restrict__ Cout, int n) {
    constexpr int AST = 136;              // 272B row stride: 16B-aligned, 2-way banks (free)
    __shared__ ushort At[64 * AST];
    __shared__ ushort Bt[NC * AST];
    int t = threadIdx.x;
    int brow = blockIdx.x * 64;
    int w = t >> 6, l = t & 63, lrow = l & 15, lk = l >> 4;

    f32x4 acc[NC / 16];
    #pragma unroll
    for (int g = 0; g < NC / 16; ++g) acc[g] = (f32x4){0.f, 0.f, 0.f, 0.f};

    #pragma unroll
    for (int src = 0; src < NSRC; ++src) {
        const ushort* A = src ? A1 : A0;
        const ushort* B = src ? B1 : B0;
        __syncthreads();                  // protect prior-iteration LDS reads
        #pragma unroll
        for (int i = 0; i < 4; ++i) {     // A: 64 rows x 16 chunks of 16B
            int c = t + 256 * i, r = c >> 4, k16 = c & 15;
            int grow = brow + r;
            uint4 v = make_uint4(0, 0, 0, 0);
            if (grow < n) v = *reinterpret_cast<const uint4*>(&A[(size_t)grow * 128 + k16 * 8]);
            *reinterpret_cast<uint4*>(&At[r * AST + k16 * 8]) = v;
        }
        #pragma unroll
        for (int i = 0; i < NC / 16; ++i) {  // B^T: NC rows x 16 chunks
            int c = t + 256 * i, r = c >> 4, k16 = c & 15;
            *reinterpret_cast<uint4*>(&Bt[r * AST + k16 * 8]) =
                *reinterpret_cast<const uint4*>(&B[(size_t)r * 128 + k16 * 8]);
        }
        __syncthreads();
        #pragma unroll
        for (int ks = 0; ks < 4; ++ks) {
            bf16x8 a = *reinterpret_cast<const bf16x8*>(&At[(w * 16 + lrow) * AST + ks * 32 + lk * 8]);
            #pragma unroll
            for (int g = 0; g < NC / 16; ++g) {
                bf16x8 b = *reinterpret_cast<const bf16x8*>(&Bt[(g * 16 + lrow) * AST + ks * 32 + lk * 8]);
                acc[g] = __builtin_amdgcn_mfma_f32_16x16x32_bf16(a, b, acc[g], 0, 0, 0);
            }
        }
    }

    int orow = brow + w * 16 + lk * 4;
    #pragma unroll
    for (int g = 0; g < NC / 16; ++g) {
        int gcol = g * 16 + lrow;
        float bv = HAS_BIAS ? bias[gcol] : 0.f;
        #pragma unroll
        for (int r = 0; r < 4; ++r) {
            int grow = orow + r;
            if (grow >= n) continue;
            float o = acc[g][r] + bv;
            if (HAS_ADD) o += b2f(addm[(size_t)grow * NC + gcol]);
            if (RELU) o = fmaxf(o, 0.f);
            if (OUT_BF16) ((ushort*)Cout)[(size_t)grow * NC + gcol] = f2b(o);
            else          ((float*)Cout)[(size_t)grow * NC + gcol] = o;
        }
    }
}

extern "C" void kernel_launch(void* const* d_in, const int* in_sizes, int n_in,
                              void* d_out, int out_size, void* d_ws, size_t ws_size,
                              hipStream_t stream) {
    const float* x   = (const float*)d_in[0];
    const int*   edge= (const int*)d_in[1];
    const float* W1l = (const float*)d_in[2];
    const float* W1r = (const float*)d_in[3];
    const float* b1  = (const float*)d_in[4];
    const float* W2l = (const float*)d_in[5];
    const float* W2r = (const float*)d_in[6];
    const float* b2  = (const float*)d_in[7];
    float* out = (float*)d_out;

    const int N = in_sizes[0] / 128;
    const int E = in_sizes[1] / 2;
    const int* srcv = edge;
    const int* dstv = edge + E;

    char* p = (char*)d_ws;
    auto alloc = [&](size_t bytes) {
        char* q = p;
        p += ((bytes + 255) & ~(size_t)255);
        return q;
    };
    int*    cnt    = (int*)alloc((size_t)N * 4);
    int*    rowptr = (int*)alloc((size_t)(N + 1) * 4);
    int*    pos    = (int*)alloc((size_t)N * 4);
    int*    csr    = (int*)alloc((size_t)E * 4);
    float*  invd   = (float*)alloc((size_t)N * 4);
    int*    bsum   = (int*)alloc((size_t)256 * 4);
    ushort* xb     = (ushort*)alloc((size_t)N * 128 * 2);
    ushort* tbuf   = (ushort*)alloc((size_t)N * 128 * 2);
    ushort* h      = (ushort*)alloc((size_t)N * 128 * 2);
    ushort* hl     = (ushort*)alloc((size_t)N * 64 * 2);
    ushort* t2     = (ushort*)alloc((size_t)N * 64 * 2);
    ushort* w1lt   = (ushort*)alloc((size_t)16384 * 2);
    ushort* w1rt   = (ushort*)alloc((size_t)16384 * 2);
    ushort* w2lt   = (ushort*)alloc((size_t)8192 * 2);
    ushort* w2rt   = (ushort*)alloc((size_t)8192 * 2);

    int nb = (N + 1023) / 1024;

    // dtype prep
    castx_k<<<(N * 32 + 255) / 256, 256, 0, stream>>>(x, xb, N * 32);
    prepw_k<<<192, 256, 0, stream>>>(W1l, W1r, W2l, W2r, w1lt, w1rt, w2lt, w2rt);

    // CSR build
    hipMemsetAsync(cnt, 0, (size_t)N * 4, stream);
    count_deg_k<<<(E + 255) / 256, 256, 0, stream>>>(dstv, cnt, E);
    blocksum_k<<<nb, 256, 0, stream>>>(cnt, bsum, N);
    bscan_k<<<1, 256, 0, stream>>>(bsum, nb);
    scanout_k<<<nb, 256, 0, stream>>>(cnt, bsum, rowptr, pos, invd, N, E);
    fill_k<<<(E + 255) / 256, 256, 0, stream>>>(srcv, dstv, pos, csr, E);

    int gb = (N + 63) / 64;
    int ag = (N + 7) / 8;       // 8 nodes per 256-thread block (half-wave per node)

    // t = mean_agg(xb)
    aggb_k<128><<<ag, 256, 0, stream>>>(xb, rowptr, csr, invd, tbuf, N);
    // h = relu(xb@W1r + t@W1l + b1) -> bf16
    mgemm_k<128, 2, true, true, true, false><<<gb, 256, 0, stream>>>(
        xb, w1rt, tbuf, w1lt, nullptr, b1, h, N);
    // hl = h@W2l -> bf16
    mgemm_k<64, 1, false, true, false, false><<<gb, 256, 0, stream>>>(
        h, w2lt, nullptr, nullptr, nullptr, nullptr, hl, N);
    // t2 = mean_agg(hl)
    aggb_k<64><<<ag, 256, 0, stream>>>(hl, rowptr, csr, invd, t2, N);
    // out = h@W2r + t2 + b2 -> fp32
    mgemm_k<64, 1, false, false, true, true><<<gb, 256, 0, stream>>>(
        h, w2rt, nullptr, nullptr, t2, b2, out, N);
}

// Round 15
// 271.607 us; speedup vs baseline: 2.2351x; 1.0685x over previous
//
#include <hip/hip_runtime.h>
#include <hip/hip_bf16.h>

// bf16 pipeline (verified R12: 290us, absmax 7.8e-3):
//   xb = bf16(x); t = mean_agg(xb); h = relu(xb@W1r + t@W1l + b1)
//   hl = h@W2l; t2 = mean_agg(hl); out = h@W2r + t2 + b2
// CSR build: histogram -> device-wide scan -> TWO-PHASE counting-sort fill:
//   bucket_k groups edges by dst>>8 into ebuf (block-batched run reservation),
//   fill2_k scatters from ebuf -> csr with line-local writes.
// (R12 profile: fill_k 55us, WRITE_SIZE 52MB for a 3.2MB csr = 16x write amp.)

typedef __attribute__((ext_vector_type(8))) short bf16x8;
typedef __attribute__((ext_vector_type(4))) float f32x4;

__device__ __forceinline__ ushort f2b(float f) {            // RNE fp32->bf16
    uint u = __float_as_uint(f);
    return (ushort)((u + 0x7fffu + ((u >> 16) & 1u)) >> 16);
}
__device__ __forceinline__ float b2f(ushort h) { return __uint_as_float(((uint)h) << 16); }
__device__ __forceinline__ float blo(uint u) { return __uint_as_float(u << 16); }
__device__ __forceinline__ float bhi(uint u) { return __uint_as_float(u & 0xffff0000u); }

// ---------------- CSR build ----------------
__global__ void count_deg_k(const int* __restrict__ dstv, int* __restrict__ cnt, int E) {
    int e = blockIdx.x * blockDim.x + threadIdx.x;
    if (e < E) atomicAdd(&cnt[dstv[e]], 1);
}

__global__ __launch_bounds__(256) void blocksum_k(const int* __restrict__ cnt,
                                                  int* __restrict__ bsum, int n) {
    __shared__ int red[4];
    int b = blockIdx.x, t = threadIdx.x;
    int base = b * 1024 + t * 4;
    int s = 0;
    #pragma unroll
    for (int i = 0; i < 4; ++i) { int idx = base + i; if (idx < n) s += cnt[idx]; }
    #pragma unroll
    for (int off = 32; off > 0; off >>= 1) s += __shfl_down(s, off);
    if ((t & 63) == 0) red[t >> 6] = s;
    __syncthreads();
    if (t == 0) bsum[b] = red[0] + red[1] + red[2] + red[3];
}

__global__ __launch_bounds__(256) void bscan_k(int* __restrict__ bsum, int nb) {
    __shared__ int sd[256];
    int t = threadIdx.x;
    int v = (t < nb) ? bsum[t] : 0;
    sd[t] = v;
    __syncthreads();
    for (int off = 1; off < 256; off <<= 1) {
        int u = (t >= off) ? sd[t - off] : 0;
        __syncthreads();
        sd[t] += u;
        __syncthreads();
    }
    if (t < nb) bsum[t] = sd[t] - v;
}

__global__ __launch_bounds__(256) void scanout_k(const int* __restrict__ cnt,
                                                 const int* __restrict__ bbase,
                                                 int* __restrict__ rowptr,
                                                 int* __restrict__ pos,
                                                 float* __restrict__ inv_deg,
                                                 int n, int E) {
    __shared__ int sums[256];
    int b = blockIdx.x, t = threadIdx.x;
    int base = b * 1024 + t * 4;
    int v[4];
    int s = 0;
    #pragma unroll
    for (int i = 0; i < 4; ++i) {
        int idx = base + i;
        v[i] = (idx < n) ? cnt[idx] : 0;
        s += v[i];
    }
    sums[t] = s;
    __syncthreads();
    for (int off = 1; off < 256; off <<= 1) {
        int u = (t >= off) ? sums[t - off] : 0;
        __syncthreads();
        sums[t] += u;
        __syncthreads();
    }
    int pre = sums[t] - s + bbase[b];
    #pragma unroll
    for (int i = 0; i < 4; ++i) {
        int idx = base + i;
        if (idx < n) {
            rowptr[idx] = pre;
            pos[idx] = pre;
            inv_deg[idx] = 1.0f / (float)max(v[i], 1);
            pre += v[i];
        }
    }
    if (b == 0 && t == 0) rowptr[n] = E;
}

// bucket bases in ebuf: bucket b covers nodes [b*256,(b+1)*256); base = rowptr[b*256]
__global__ void bucketbase_k(const int* __restrict__ rowptr, int* __restrict__ bucketPos,
                             int nbuckets) {
    int b = blockIdx.x * blockDim.x + threadIdx.x;
    if (b < nbuckets) bucketPos[b] = rowptr[b * 256];
}

// Phase A: group edges by coarse bucket dst>>8 into ebuf (dst,src pairs).
// Block-batched: LDS histogram -> one global atomic per bucket -> grouped writes.
__global__ __launch_bounds__(256) void bucket_k(const int* __restrict__ srcv,
                                                const int* __restrict__ dstv,
                                                int* __restrict__ bucketPos,
                                                uint2* __restrict__ ebuf, int E) {
    __shared__ int hist[256], rbase[256];
    int t = threadIdx.x;
    int e0 = blockIdx.x * 2048;
    hist[t] = 0;
    __syncthreads();
    int d[8], s[8];
    #pragma unroll
    for (int i = 0; i < 8; ++i) {
        int e = e0 + t + 256 * i;
        if (e < E) {
            d[i] = dstv[e]; s[i] = srcv[e];
            atomicAdd(&hist[d[i] >> 8], 1);
        } else d[i] = -1;
    }
    __syncthreads();
    if (hist[t] > 0) rbase[t] = atomicAdd(&bucketPos[t], hist[t]);
    __syncthreads();
    hist[t] = 0;
    __syncthreads();
    #pragma unroll
    for (int i = 0; i < 8; ++i) {
        if (d[i] >= 0) {
            int b = d[i] >> 8;
            int off = atomicAdd(&hist[b], 1);
            ebuf[rbase[b] + off] = make_uint2((uint)d[i], (uint)s[i]);
        }
    }
}

// Phase B: scatter from bucket-grouped ebuf -> csr. A wave's 64 edges share a
// ~256-node window, so csr writes are line-local in space and time.
__global__ void fill2_k(const uint2* __restrict__ ebuf, int* __restrict__ pos,
                        int* __restrict__ csr, int E) {
    int e = blockIdx.x * blockDim.x + threadIdx.x;
    if (e < E) {
        uint2 v = ebuf[e];
        int p = atomicAdd(&pos[v.x], 1);
        csr[p] = (int)v.y;
    }
}

// ---------------- dtype prep ----------------
__global__ void castx_k(const float* __restrict__ x, ushort* __restrict__ xb, int total4) {
    int i = blockIdx.x * blockDim.x + threadIdx.x;
    if (i < total4) {
        float4 v = reinterpret_cast<const float4*>(x)[i];
        ushort4 r;
        r.x = f2b(v.x); r.y = f2b(v.y); r.z = f2b(v.z); r.w = f2b(v.w);
        reinterpret_cast<ushort4*>(xb)[i] = r;
    }
}

// W^T (bf16, [n][k], k contiguous) for all four weights in one launch.
__global__ void prepw_k(const float* __restrict__ W1l, const float* __restrict__ W1r,
                        const float* __restrict__ W2l, const float* __restrict__ W2r,
                        ushort* __restrict__ w1lt, ushort* __restrict__ w1rt,
                        ushort* __restrict__ w2lt, ushort* __restrict__ w2rt) {
    int i = blockIdx.x * blockDim.x + threadIdx.x;   // 0..49151
    if (i < 16384) {
        int nn = i >> 7, k = i & 127;
        w1lt[i] = f2b(W1l[k * 128 + nn]);
    } else if (i < 32768) {
        int j = i - 16384, nn = j >> 7, k = j & 127;
        w1rt[j] = f2b(W1r[k * 128 + nn]);
    } else if (i < 40960) {
        int j = i - 32768, nn = j >> 7, k = j & 127;
        w2lt[j] = f2b(W2l[k * 64 + nn]);
    } else if (i < 49152) {
        int j = i - 40960, nn = j >> 7, k = j & 127;
        w2rt[j] = f2b(W2r[k * 64 + nn]);
    }
}

// ---------------- bf16 mean-aggregation: half-wave per node, 2-edge unroll ----------------
template<int F>
__global__ __launch_bounds__(256) void aggb_k(const ushort* __restrict__ feat,
                                              const int* __restrict__ rowptr,
                                              const int* __restrict__ csr,
                                              const float* __restrict__ invd,
                                              ushort* __restrict__ out, int n) {
    int tid = blockIdx.x * 256 + threadIdx.x;
    int node = tid >> 5;
    int sl = threadIdx.x & 31;
    if (node >= n) return;
    int s = rowptr[node], e = rowptr[node + 1];
    float sc = invd[node];
    if (F == 128) {           // lane owns 4 bf16 (8B); half-wave row = 256B
        float a0 = 0, a1 = 0, a2 = 0, a3 = 0;
        int p = s;
        for (; p + 2 <= e; p += 2) {
            int u0 = csr[p], u1 = csr[p + 1];
            uint2 v0 = *reinterpret_cast<const uint2*>(&feat[(size_t)u0 * 128 + sl * 4]);
            uint2 v1 = *reinterpret_cast<const uint2*>(&feat[(size_t)u1 * 128 + sl * 4]);
            a0 += blo(v0.x); a1 += bhi(v0.x); a2 += blo(v0.y); a3 += bhi(v0.y);
            a0 += blo(v1.x); a1 += bhi(v1.x); a2 += blo(v1.y); a3 += bhi(v1.y);
        }
        if (p < e) {
            uint2 v0 = *reinterpret_cast<const uint2*>(&feat[(size_t)csr[p] * 128 + sl * 4]);
            a0 += blo(v0.x); a1 += bhi(v0.x); a2 += blo(v0.y); a3 += bhi(v0.y);
        }
        ushort4 r;
        r.x = f2b(a0 * sc); r.y = f2b(a1 * sc); r.z = f2b(a2 * sc); r.w = f2b(a3 * sc);
        *reinterpret_cast<ushort4*>(&out[(size_t)node * 128 + sl * 4]) = r;
    } else {                  // F==64: lane owns 2 bf16 (4B); half-wave row = 128B
        float a0 = 0, a1 = 0;
        int p = s;
        for (; p + 2 <= e; p += 2) {
            int u0 = csr[p], u1 = csr[p + 1];
            uint v0 = *reinterpret_cast<const uint*>(&feat[(size_t)u0 * 64 + sl * 2]);
            uint v1 = *reinterpret_cast<const uint*>(&feat[(size_t)u1 * 64 + sl * 2]);
            a0 += blo(v0) + blo(v1); a1 += bhi(v0) + bhi(v1);
        }
        if (p < e) {
            uint v0 = *reinterpret_cast<const uint*>(&feat[(size_t)csr[p] * 64 + sl * 2]);
            a0 += blo(v0); a1 += bhi(v0);
        }
        ushort2 r;
        r.x = f2b(a0 * sc); r.y = f2b(a1 * sc);
        *reinterpret_cast<ushort2*>(&out[(size_t)node * 64 + sl * 2]) = r;
    }
}

// ---------------- MFMA GEMM: C[n,NC] = sum_src A_s[n,128] @ B_s[128,NC] (+add)(+bias)(relu)
// B passed pre-transposed bf16 [NC][128] (k contiguous). 64 rows/block, 4 waves,
// wave covers 16 rows x NC cols. 16x16x32 bf16 MFMA; C/D: col=lane&15, row=(lane>>4)*4+r.
template<int NC, int NSRC, bool RELU, bool OUT_BF16, bool HAS_BIAS, bool HAS_ADD>
__global__ __launch_bounds__(256) void mgemm_k(const ushort* __restrict__ A0,
                                               const ushort* __restrict__ B0,
                                               const ushort* __restrict__ A1,
                                               const ushort* __restrict__ B1,
                                               const ushort* __restrict__ addm,
                                               const float* __restrict__ bias,
                                               void* __restrict__ Cout, int n) {
    constexpr int AST = 136;              // 272B row stride: 16B-aligned, 2-way banks (free)
    __shared__ ushort At[64 * AST];
    __shared__ ushort Bt[NC * AST];
    int t = threadIdx.x;
    int brow = blockIdx.x * 64;
    int w = t >> 6, l = t & 63, lrow = l & 15, lk = l >> 4;

    f32x4 acc[NC / 16];
    #pragma unroll
    for (int g = 0; g < NC / 16; ++g) acc[g] = (f32x4){0.f, 0.f, 0.f, 0.f};

    #pragma unroll
    for (int src = 0; src < NSRC; ++src) {
        const ushort* A = src ? A1 : A0;
        const ushort* B = src ? B1 : B0;
        __syncthreads();                  // protect prior-iteration LDS reads
        #pragma unroll
        for (int i = 0; i < 4; ++i) {     // A: 64 rows x 16 chunks of 16B
            int c = t + 256 * i, r = c >> 4, k16 = c & 15;
            int grow = brow + r;
            uint4 v = make_uint4(0, 0, 0, 0);
            if (grow < n) v = *reinterpret_cast<const uint4*>(&A[(size_t)grow * 128 + k16 * 8]);
            *reinterpret_cast<uint4*>(&At[r * AST + k16 * 8]) = v;
        }
        #pragma unroll
        for (int i = 0; i < NC / 16; ++i) {  // B^T: NC rows x 16 chunks
            int c = t + 256 * i, r = c >> 4, k16 = c & 15;
            *reinterpret_cast<uint4*>(&Bt[r * AST + k16 * 8]) =
                *reinterpret_cast<const uint4*>(&B[(size_t)r * 128 + k16 * 8]);
        }
        __syncthreads();
        #pragma unroll
        for (int ks = 0; ks < 4; ++ks) {
            bf16x8 a = *reinterpret_cast<const bf16x8*>(&At[(w * 16 + lrow) * AST + ks * 32 + lk * 8]);
            #pragma unroll
            for (int g = 0; g < NC / 16; ++g) {
                bf16x8 b = *reinterpret_cast<const bf16x8*>(&Bt[(g * 16 + lrow) * AST + ks * 32 + lk * 8]);
                acc[g] = __builtin_amdgcn_mfma_f32_16x16x32_bf16(a, b, acc[g], 0, 0, 0);
            }
        }
    }

    int orow = brow + w * 16 + lk * 4;
    #pragma unroll
    for (int g = 0; g < NC / 16; ++g) {
        int gcol = g * 16 + lrow;
        float bv = HAS_BIAS ? bias[gcol] : 0.f;
        #pragma unroll
        for (int r = 0; r < 4; ++r) {
            int grow = orow + r;
            if (grow >= n) continue;
            float o = acc[g][r] + bv;
            if (HAS_ADD) o += b2f(addm[(size_t)grow * NC + gcol]);
            if (RELU) o = fmaxf(o, 0.f);
            if (OUT_BF16) ((ushort*)Cout)[(size_t)grow * NC + gcol] = f2b(o);
            else          ((float*)Cout)[(size_t)grow * NC + gcol] = o;
        }
    }
}

extern "C" void kernel_launch(void* const* d_in, const int* in_sizes, int n_in,
                              void* d_out, int out_size, void* d_ws, size_t ws_size,
                              hipStream_t stream) {
    const float* x   = (const float*)d_in[0];
    const int*   edge= (const int*)d_in[1];
    const float* W1l = (const float*)d_in[2];
    const float* W1r = (const float*)d_in[3];
    const float* b1  = (const float*)d_in[4];
    const float* W2l = (const float*)d_in[5];
    const float* W2r = (const float*)d_in[6];
    const float* b2  = (const float*)d_in[7];
    float* out = (float*)d_out;

    const int N = in_sizes[0] / 128;
    const int E = in_sizes[1] / 2;
    const int* srcv = edge;
    const int* dstv = edge + E;

    char* p = (char*)d_ws;
    auto alloc = [&](size_t bytes) {
        char* q = p;
        p += ((bytes + 255) & ~(size_t)255);
        return q;
    };
    int*    cnt    = (int*)alloc((size_t)N * 4);
    int*    rowptr = (int*)alloc((size_t)(N + 1) * 4);
    int*    pos    = (int*)alloc((size_t)N * 4);
    int*    csr    = (int*)alloc((size_t)E * 4);
    float*  invd   = (float*)alloc((size_t)N * 4);
    int*    bsum   = (int*)alloc((size_t)256 * 4);
    int*    bktpos = (int*)alloc((size_t)256 * 4);
    uint2*  ebuf   = (uint2*)alloc((size_t)E * 8);
    ushort* xb     = (ushort*)alloc((size_t)N * 128 * 2);
    ushort* tbuf   = (ushort*)alloc((size_t)N * 128 * 2);
    ushort* h      = (ushort*)alloc((size_t)N * 128 * 2);
    ushort* hl     = (ushort*)alloc((size_t)N * 64 * 2);
    ushort* t2     = (ushort*)alloc((size_t)N * 64 * 2);
    ushort* w1lt   = (ushort*)alloc((size_t)16384 * 2);
    ushort* w1rt   = (ushort*)alloc((size_t)16384 * 2);
    ushort* w2lt   = (ushort*)alloc((size_t)8192 * 2);
    ushort* w2rt   = (ushort*)alloc((size_t)8192 * 2);

    int nb = (N + 1023) / 1024;
    int nbuckets = (N + 255) / 256;   // 196 for N=50000 (fits <=256)

    // dtype prep
    castx_k<<<(N * 32 + 255) / 256, 256, 0, stream>>>(x, xb, N * 32);
    prepw_k<<<192, 256, 0, stream>>>(W1l, W1r, W2l, W2r, w1lt, w1rt, w2lt, w2rt);

    // CSR build
    hipMemsetAsync(cnt, 0, (size_t)N * 4, stream);
    count_deg_k<<<(E + 255) / 256, 256, 0, stream>>>(dstv, cnt, E);
    blocksum_k<<<nb, 256, 0, stream>>>(cnt, bsum, N);
    bscan_k<<<1, 256, 0, stream>>>(bsum, nb);
    scanout_k<<<nb, 256, 0, stream>>>(cnt, bsum, rowptr, pos, invd, N, E);
    bucketbase_k<<<1, 256, 0, stream>>>(rowptr, bktpos, nbuckets);
    bucket_k<<<(E + 2047) / 2048, 256, 0, stream>>>(srcv, dstv, bktpos, ebuf, E);
    fill2_k<<<(E + 255) / 256, 256, 0, stream>>>(ebuf, pos, csr, E);

    int gb = (N + 63) / 64;
    int ag = (N + 7) / 8;       // 8 nodes per 256-thread block (half-wave per node)

    // t = mean_agg(xb)
    aggb_k<128><<<ag, 256, 0, stream>>>(xb, rowptr, csr, invd, tbuf, N);
    // h = relu(xb@W1r + t@W1l + b1) -> bf16
    mgemm_k<128, 2, true, true, true, false><<<gb, 256, 0, stream>>>(
        xb, w1rt, tbuf, w1lt, nullptr, b1, h, N);
    // hl = h@W2l -> bf16
    mgemm_k<64, 1, false, true, false, false><<<gb, 256, 0, stream>>>(
        h, w2lt, nullptr, nullptr, nullptr, nullptr, hl, N);
    // t2 = mean_agg(hl)
    aggb_k<64><<<ag, 256, 0, stream>>>(hl, rowptr, csr, invd, t2, N);
    // out = h@W2r + t2 + b2 -> fp32
    mgemm_k<64, 1, false, false, true, true><<<gb, 256, 0, stream>>>(
        h, w2rt, nullptr, nullptr, t2, b2, out, N);
}